// Round 7
// baseline (376.278 us; speedup 1.0000x reference)
//
#include <hip/hip_runtime.h>
#include <hip/hip_bf16.h>
#include <math.h>

// MHA block: B=4, S=2048, D=1024, H=16, DK=64.
// R11 (resubmit after infra failure): (a) RoPE cos/sin TABLE (S x DK/2 float2,
// 512KB, built in cvt6) replaces 64 __sincosf + 4 exp2f per thread in the GEMM
// rope epilogue -- that trig was ~1000-1600 VALU cyc/thread, same order as the
// whole K-loop's MFMA issue. Table math is op-identical (exp2f + __sincosf at
// build time) -> bit-identical output. (b) attn: T5 s_setprio(1) around QK/PV
// MFMA clusters (4 independent blocks/CU at unsynced phases = role diversity;
// m191 +4-7%).
// R10 lesson kept: SQ_LDS_BANK_CONFLICT=8519680 is a gl_lds DMA artifact, not
// a lever; attn softmax VALU is not the wall (c2-fold was null).

namespace {

constexpr int Bb = 4, Ss = 2048, Dd = 1024, Hh = 16, DKk = 64;
constexpr size_t NElem = (size_t)Bb * Hh * Ss * DKk;  // 8388608
constexpr size_t WElem = (size_t)Dd * Dd;             // 1048576
constexpr int TabN = Ss * (DKk / 2);                  // 65536 float2 entries

typedef __bf16 bf16;
typedef __attribute__((ext_vector_type(8))) __bf16 bf16x8;
typedef __attribute__((ext_vector_type(4))) float f32x4;

__device__ __forceinline__ bf16x8 pack8(float4 a, float4 b) {
  bf16x8 r;
  r[0] = (__bf16)a.x; r[1] = (__bf16)a.y; r[2] = (__bf16)a.z; r[3] = (__bf16)a.w;
  r[4] = (__bf16)b.x; r[5] = (__bf16)b.y; r[6] = (__bf16)b.z; r[7] = (__bf16)b.w;
  return r;
}

__device__ __forceinline__ void gl_lds16(const bf16* g, bf16* l) {
  __builtin_amdgcn_global_load_lds((const __attribute__((address_space(1))) void*)g,
                                   (__attribute__((address_space(3))) void*)l, 16, 0, 0);
}

__device__ __forceinline__ void rope_tab_entry(int idx, float2* tab) {
  const int p = idx & 31, s = idx >> 5;
  const float invf = exp2f((float)p * -0.4152410118609203f);
  float sn, cs;
  __sincosf((float)s * invf, &sn, &cs);
  tab[idx] = make_float2(cs, sn);
}

// fused fp32->bf16 + rope-table build:
// [0,12288) convert q,k,v (4096 each); [12288,14336) convert wq,wk,wv,wo
// (512 each); [14336,14592) build rope table (65536 float2).
__global__ __launch_bounds__(256) void cvt6(const float* __restrict__ q,
                                            const float* __restrict__ k,
                                            const float* __restrict__ v,
                                            const float* __restrict__ wq,
                                            const float* __restrict__ wk,
                                            const float* __restrict__ wv,
                                            const float* __restrict__ wo,
                                            bf16* __restrict__ xd, bf16* __restrict__ wd,
                                            float2* __restrict__ tab) {
  const int bid = blockIdx.x;
  if (bid >= 14336) {
    rope_tab_entry((bid - 14336) * 256 + threadIdx.x, tab);
    return;
  }
  const float* s; bf16* d; size_t idx;
  if (bid < 12288) {
    const int t = bid >> 12;
    s = (t == 0) ? q : (t == 1) ? k : v;
    d = xd + (size_t)t * NElem;
    idx = ((size_t)(bid & 4095) * 256 + threadIdx.x) * 8;
  } else {
    const int t = (bid - 12288) >> 9;
    s = (t == 0) ? wq : (t == 1) ? wk : (t == 2) ? wv : wo;
    d = wd + (size_t)t * WElem;
    idx = ((size_t)((bid - 12288) & 511) * 256 + threadIdx.x) * 8;
  }
  float4 f0 = *(const float4*)(s + idx), f1 = *(const float4*)(s + idx + 4);
  *(bf16x8*)(d + idx) = pack8(f0, f1);
}

// standalone rope-table build (fallback path)
__global__ __launch_bounds__(256) void rope_tab_k(float2* __restrict__ tab) {
  rope_tab_entry(blockIdx.x * 256 + threadIdx.x, tab);
}

// legacy pair-convert for the fallback path
__global__ __launch_bounds__(256) void cvt_pair(const float* __restrict__ x, bf16* __restrict__ xd,
                                                const float* __restrict__ ws, bf16* __restrict__ wd) {
  const int bid = blockIdx.x;
  const float* s; bf16* d; size_t idx;
  if (bid < 4096) { s = x; d = xd; idx = (size_t)bid * 256 + threadIdx.x; }
  else { s = ws; d = wd; idx = (size_t)(bid - 4096) * 256 + threadIdx.x; }
  idx *= 8;
  float4 f0 = *(const float4*)(s + idx), f1 = *(const float4*)(s + idx + 4);
  *(bf16x8*)(d + idx) = pack8(f0, f1);
}

__global__ __launch_bounds__(256) void cvt_w(const float* __restrict__ ws, bf16* __restrict__ wd) {
  size_t idx = ((size_t)blockIdx.x * 256 + threadIdx.x) * 8;
  float4 f0 = *(const float4*)(ws + idx), f1 = *(const float4*)(ws + idx + 4);
  *(bf16x8*)(wd + idx) = pack8(f0, f1);
}

// C = A(8192x1024) * W(1024x1024)^T, bf16 in, 128x128 tile, BK=32, 4 waves (2x2 of 64x64).
// Double-buffered global_load_lds prefetch. MODE 0: rope-store; 1: V-transpose-store;
// 2: fp32 plain store (out proj); 3: fused QKV (blockIdx.z selects tensor; z<2 rope,
// z==2 transpose). Rope epilogue reads the precomputed cos/sin table (L1/L2-hot).
template <int MODE>
__global__ __launch_bounds__(256, 4) void mha_gemm(const bf16* __restrict__ A,
                                                   const bf16* __restrict__ W,
                                                   void* __restrict__ dstv,
                                                   const float2* __restrict__ tab) {
  __shared__ __align__(16) bf16 As[2][128][32];
  __shared__ __align__(16) bf16 Bs[2][128][32];
  const int tid = threadIdx.x;
  const int z = (MODE == 3) ? blockIdx.z : 0;
  const int bm0 = blockIdx.x * 128, bn0 = blockIdx.y * 128;
  const int w = tid >> 6, lane = tid & 63, l16 = lane & 15, quad = lane >> 4;
  const int wm = (w >> 1) * 64, wn = (w & 1) * 64;
  const int lr = lane >> 2, lc = (lane & 3) * 8;

  const bf16* Ag = A + (size_t)z * NElem + (size_t)(bm0 + w * 32 + lr) * Dd + lc;
  const bf16* Wg = W + (size_t)z * WElem + (size_t)(bn0 + w * 32 + lr) * Dd + lc;

  f32x4 acc[4][4] = {};

  // prologue: stage k-tile 0 into buf 0
  gl_lds16(Ag, &As[0][w * 32][0]);
  gl_lds16(Ag + 16 * Dd, &As[0][w * 32 + 16][0]);
  gl_lds16(Wg, &Bs[0][w * 32][0]);
  gl_lds16(Wg + 16 * Dd, &Bs[0][w * 32 + 16][0]);
  __syncthreads();

  for (int kt = 0; kt < 32; ++kt) {
    const int cur = kt & 1, nxt = cur ^ 1;
    if (kt < 31) {
      const int ko = (kt + 1) * 32;
      gl_lds16(Ag + ko, &As[nxt][w * 32][0]);
      gl_lds16(Ag + ko + 16 * Dd, &As[nxt][w * 32 + 16][0]);
      gl_lds16(Wg + ko, &Bs[nxt][w * 32][0]);
      gl_lds16(Wg + ko + 16 * Dd, &Bs[nxt][w * 32 + 16][0]);
    }
    bf16x8 af[4], bw[4];
#pragma unroll
    for (int i = 0; i < 4; ++i) af[i] = *(bf16x8*)&As[cur][wm + i * 16 + l16][quad * 8];
#pragma unroll
    for (int i = 0; i < 4; ++i) bw[i] = *(bf16x8*)&Bs[cur][wn + i * 16 + l16][quad * 8];
#pragma unroll
    for (int mt = 0; mt < 4; ++mt)
#pragma unroll
      for (int nt = 0; nt < 4; ++nt)
        acc[mt][nt] =
            __builtin_amdgcn_mfma_f32_16x16x32_bf16(af[mt], bw[nt], acc[mt][nt], 0, 0, 0);
    __syncthreads();  // drains nxt DMA (issued before compute) + orders LDS reuse
  }

  // C/D layout: col = lane&15, row = quad*4 + r
  const bool do_rope = (MODE == 0) || (MODE == 3 && z < 2);
  const bool do_vt = (MODE == 1) || (MODE == 3 && z == 2);

  if constexpr (MODE == 2) {
    float* out = (float*)dstv;
#pragma unroll
    for (int mt = 0; mt < 4; ++mt)
#pragma unroll
      for (int nt = 0; nt < 4; ++nt) {
        const int gcol = bn0 + wn + nt * 16 + l16;
        const int grow0 = bm0 + wm + mt * 16 + quad * 4;
#pragma unroll
        for (int r = 0; r < 4; ++r) out[(size_t)(grow0 + r) * Dd + gcol] = acc[mt][nt][r];
      }
  } else {
    if (do_vt) {
      bf16* vt = (bf16*)dstv + (MODE == 3 ? 2 * NElem : 0);
#pragma unroll
      for (int mt = 0; mt < 4; ++mt)
#pragma unroll
        for (int nt = 0; nt < 4; ++nt) {
          const int gcol = bn0 + wn + nt * 16 + l16;
          const int h = gcol >> 6, dk = gcol & 63;
#pragma unroll
          for (int r = 0; r < 4; ++r) {
            const int grow = bm0 + wm + mt * 16 + quad * 4 + r;
            const int b = grow >> 11, s = grow & (Ss - 1);
            vt[((size_t)(b * Hh + h) * DKk + dk) * Ss + s] = (bf16)acc[mt][nt][r];
          }
        }
    } else if (do_rope) {
      bf16* qp = (bf16*)dstv + (MODE == 3 ? (size_t)z * NElem : 0);
#pragma unroll
      for (int mt = 0; mt < 4; ++mt)
#pragma unroll
        for (int nt = 0; nt < 4; ++nt) {
          const int gcol = bn0 + wn + nt * 16 + l16;
          const int h = gcol >> 6;
          const int dk = nt * 16 + l16;  // == gcol & 63 (bn0 mult of 128, wn in {0,64})
          const int p = dk >> 1;
          const float sgn = (dk & 1) ? 1.0f : -1.0f;
#pragma unroll
          for (int r = 0; r < 4; ++r) {
            const int grow = bm0 + wm + mt * 16 + quad * 4 + r;
            const int b = grow >> 11, s = grow & (Ss - 1);
            const float v = acc[mt][nt][r];
            const float ov = __shfl_xor(v, 1);
            const float2 cs = tab[s * 32 + p];
            const float rot = v * cs.x + sgn * ov * cs.y;
            qp[((size_t)(b * Hh + h) * Ss + s) * DKk + dk] = (bf16)rot;
          }
        }
    }
  }
}

// Flash attention (R6 structure + T5 setprio): 128 q-rows x one (b,h) per block;
// 4 waves x 32 rows; 64-key tiles, double-buffered gl_lds; mask folded into MFMA
// acc init (bias -96); l via ones-MFMA; per-kt phase split with single-pass
// kf/vf reads. s_setprio(1) wraps the QK and PV MFMA clusters (T5).
// LDS: Ks 16K dbuf + Vs 16K dbuf + P 8K = 40960 B -> 4 blocks/CU.
__global__ __launch_bounds__(256, 4) void mha_attn(const bf16* __restrict__ Qp,
                                                   const bf16* __restrict__ Kp,
                                                   const bf16* __restrict__ Vt,
                                                   const int* __restrict__ maskG,
                                                   bf16* __restrict__ Xo) {
  __shared__ __align__(16) bf16 Ks[2][64][64];  // [buf][key][dk], XOR-swizzled 16B chunks
  __shared__ __align__(16) bf16 Vs[2][64][64];  // [buf][dk][key], XOR-swizzled 16B chunks
  __shared__ __align__(16) bf16 Pbuf[4][1024];  // per-wave P slice (16 rows x 64 keys)

  constexpr float c1 = 0.18033688011112042f;   // 0.125 * log2(e)
  // c2 = -12*log2(e) folded into acc-init bias: -c2/c1 = -96 exactly.

  const int tid = threadIdx.x;
  const int bh = blockIdx.y, b = bh >> 4, h = bh & 15;
  const int q0 = blockIdx.x * 128;
  const int w = tid >> 6, lane = tid & 63, l16 = lane & 15, quad = lane >> 4;
  const int swz = l16 & 7;
  const size_t hbase = (size_t)bh * Ss * DKk;

  {  // stage Q tile [128 x 64] through the Ks dbuf area (8192 elts, exactly fits)
    bf16* Qst = &Ks[0][0][0];
    const int row = tid >> 1, hf = tid & 1;
    const bf16* src = Qp + hbase + (size_t)(q0 + row) * DKk + hf * 32;
#pragma unroll
    for (int cc = 0; cc < 4; ++cc)
      *(int4*)&Qst[(((hf * 4 + cc) * 128) + row) * 8] = *(const int4*)(src + cc * 8);
  }
  __syncthreads();
  // hoist Q fragments (A-layout: m -> q-row w*32+mt*16+l16, k=kk*32+quad*8+j)
  bf16x8 qf[2][2];
  {
    const bf16* Qst = &Ks[0][0][0];
#pragma unroll
    for (int mt = 0; mt < 2; ++mt)
#pragma unroll
      for (int kk = 0; kk < 2; ++kk)
        qf[mt][kk] = *(bf16x8*)&Qst[(((kk * 4 + quad) * 128) + w * 32 + mt * 16 + l16) * 8];
  }
  __syncthreads();  // all hoists done before K DMA overwrites Ks

  // staging lane geometry: 8 rows x 8 chunks per issue; swizzle chunk ^= row&7
  const int srow = lane >> 3, schunk = (lane & 7) ^ (srow & 7);
  const bf16* Kg = Kp + hbase + (size_t)(w * 16 + srow) * DKk + schunk * 8;
  const bf16* Vg = Vt + ((size_t)bh * DKk + w * 16 + srow) * Ss + schunk * 8;
  const int* Mg = maskG + b * Ss + l16;

  int mcur[4], mnext[4];
  // prologue: stage tile 0
#pragma unroll
  for (int i = 0; i < 2; ++i) {
    gl_lds16(Kg + (size_t)i * 8 * DKk, &Ks[0][w * 16 + i * 8][0]);
    gl_lds16(Vg + i * 8 * Ss, &Vs[0][w * 16 + i * 8][0]);
  }
#pragma unroll
  for (int nt = 0; nt < 4; ++nt) mcur[nt] = Mg[nt * 16];
  __syncthreads();  // drains tile-0 DMA

  f32x4 o[2][4] = {};
  f32x4 lo[2] = {};
  bf16* Pb = &Pbuf[w][0];

  // ones B-operand for the l-accumulating MFMA (registers only, no LDS)
  bf16x8 vones;
#pragma unroll
  for (int i = 0; i < 8; ++i) vones[i] = (__bf16)1.0f;

  for (int kt = 0; kt < 32; ++kt) {
    const int cur = kt & 1, nxt = cur ^ 1;
    if (kt < 31) {  // prefetch tile kt+1 (drained at this iteration's end barrier)
      const size_t k0n = (size_t)(kt + 1) * 64;
#pragma unroll
      for (int i = 0; i < 2; ++i) {
        gl_lds16(Kg + k0n * DKk + (size_t)i * 8 * DKk, &Ks[nxt][w * 16 + i * 8][0]);
        gl_lds16(Vg + k0n + i * 8 * Ss, &Vs[nxt][w * 16 + i * 8][0]);
      }
#pragma unroll
      for (int nt = 0; nt < 4; ++nt) mnext[nt] = Mg[k0n + nt * 16];
    }

    // ---- QK phase: S = Q K^T for BOTH mt, each kf read ONCE ----
    // bias init: unmasked -96 (= -c2/c1), masked -1e9 -> exp2 underflows to 0
    f32x4 sc[2][4];
#pragma unroll
    for (int nt = 0; nt < 4; ++nt) {
      const float bv = (mcur[nt] != 0) ? -96.0f : -1e9f;
#pragma unroll
      for (int r = 0; r < 4; ++r) { sc[0][nt][r] = bv; sc[1][nt][r] = bv; }
    }
    __builtin_amdgcn_s_setprio(1);
#pragma unroll
    for (int kk = 0; kk < 2; ++kk)
#pragma unroll
      for (int nt = 0; nt < 4; ++nt) {
        bf16x8 kf = *(bf16x8*)&Ks[cur][nt * 16 + l16][((kk * 4 + quad) ^ swz) * 8];
        sc[0][nt] = __builtin_amdgcn_mfma_f32_16x16x32_bf16(qf[0][kk], kf, sc[0][nt], 0, 0, 0);
        sc[1][nt] = __builtin_amdgcn_mfma_f32_16x16x32_bf16(qf[1][kk], kf, sc[1][nt], 0, 0, 0);
      }
    __builtin_amdgcn_s_setprio(0);

    // ---- softmax + P staging, mt0 then mt1 through the SAME Pb slice ----
    // (same-wave DS ops execute in order: write mt0 -> read pf0 -> write mt1
    //  -> read pf1 is safe)
    bf16x8 pf0[2], pf1[2];
#pragma unroll
    for (int nt = 0; nt < 4; ++nt) {
      const int c = nt * 2 + (l16 >> 3);
      const int jj = l16 & 7;
#pragma unroll
      for (int r = 0; r < 4; ++r)
        Pb[(c * 16 + quad * 4 + r) * 8 + jj] = (bf16)exp2f(sc[0][nt][r] * c1);
    }
#pragma unroll
    for (int kk = 0; kk < 2; ++kk)
      pf0[kk] = *(bf16x8*)(Pb + ((kk * 4 + quad) * 16 + l16) * 8);
#pragma unroll
    for (int nt = 0; nt < 4; ++nt) {
      const int c = nt * 2 + (l16 >> 3);
      const int jj = l16 & 7;
#pragma unroll
      for (int r = 0; r < 4; ++r)
        Pb[(c * 16 + quad * 4 + r) * 8 + jj] = (bf16)exp2f(sc[1][nt][r] * c1);
    }
#pragma unroll
    for (int kk = 0; kk < 2; ++kk)
      pf1[kk] = *(bf16x8*)(Pb + ((kk * 4 + quad) * 16 + l16) * 8);

    // ---- PV phase: each vf read ONCE, feeds both mt; l via ones-MFMA ----
    __builtin_amdgcn_s_setprio(1);
#pragma unroll
    for (int kk = 0; kk < 2; ++kk) {
      lo[0] = __builtin_amdgcn_mfma_f32_16x16x32_bf16(pf0[kk], vones, lo[0], 0, 0, 0);
      lo[1] = __builtin_amdgcn_mfma_f32_16x16x32_bf16(pf1[kk], vones, lo[1], 0, 0, 0);
#pragma unroll
      for (int nt = 0; nt < 4; ++nt) {
        bf16x8 vf = *(bf16x8*)&Vs[cur][nt * 16 + l16][((kk * 4 + quad) ^ swz) * 8];
        o[0][nt] = __builtin_amdgcn_mfma_f32_16x16x32_bf16(pf0[kk], vf, o[0][nt], 0, 0, 0);
        o[1][nt] = __builtin_amdgcn_mfma_f32_16x16x32_bf16(pf1[kk], vf, o[1][nt], 0, 0, 0);
      }
    }
    __builtin_amdgcn_s_setprio(0);
    __syncthreads();  // all waves done with buf cur; prefetch of nxt drained here
#pragma unroll
    for (int nt = 0; nt < 4; ++nt) mcur[nt] = mnext[nt];
  }

  // epilogue: O / l -> Xo [B*S, H*DK] bf16  (lo identical across the 16 cols of a row)
#pragma unroll
  for (int mt = 0; mt < 2; ++mt)
#pragma unroll
    for (int nt = 0; nt < 4; ++nt)
#pragma unroll
      for (int r = 0; r < 4; ++r) {
        const int srw = q0 + w * 32 + mt * 16 + quad * 4 + r;
        const int dk = nt * 16 + l16;
        Xo[(size_t)(b * Ss + srw) * Dd + h * DKk + dk] = (bf16)(o[mt][nt][r] / lo[mt][r]);
      }
}

}  // namespace

extern "C" void kernel_launch(void* const* d_in, const int* in_sizes, int n_in,
                              void* d_out, int out_size, void* d_ws, size_t ws_size,
                              hipStream_t stream) {
  (void)in_sizes; (void)n_in; (void)out_size;
  const float* q = (const float*)d_in[0];
  const float* k = (const float*)d_in[1];
  const float* v = (const float*)d_in[2];
  const int* mask = (const int*)d_in[3];
  const float* w_q = (const float*)d_in[4];
  const float* w_k = (const float*)d_in[5];
  const float* w_v = (const float*)d_in[6];
  const float* w_o = (const float*)d_in[7];
  float* out = (float*)d_out;

  dim3 blk(256);
  const size_t fused_bytes =
      (6 * NElem + 4 * WElem) * sizeof(bf16) + (size_t)TabN * sizeof(float2);  // ~110 MB

  if (ws_size >= fused_bytes) {
    // fused path: Ab = xq,xk,xv bf16 | Wb = wq,wk,wv,wo bf16 | Db = Qp,Kp,Vt | tab
    bf16* Ab = (bf16*)d_ws;
    bf16* Wb = Ab + 3 * NElem;
    bf16* Db = Wb + 4 * WElem;
    bf16* Qp = Db;
    bf16* Kp = Db + NElem;
    bf16* Vt = Db + 2 * NElem;
    float2* tab = (float2*)(Db + 3 * NElem);
    bf16* Xo = Ab;  // xq dead after QKV GEMMs

    cvt6<<<14592, blk, 0, stream>>>(q, k, v, w_q, w_k, w_v, w_o, Ab, Wb, tab);
    mha_gemm<3><<<dim3(64, 8, 3), blk, 0, stream>>>(Ab, Wb, (void*)Db, tab);
    mha_attn<<<dim3(16, 64), blk, 0, stream>>>(Qp, Kp, Vt, mask, Xo);
    mha_gemm<2><<<dim3(64, 8), blk, 0, stream>>>(Xo, Wb + 3 * WElem, (void*)out, tab);
  } else {
    // fallback: sequential (R7 layout + tab, ~69.7 MB)
    bf16* buf0 = (bf16*)d_ws;
    bf16* wbuf = buf0 + NElem;
    bf16* Qp = wbuf + WElem;
    bf16* Kp = Qp + NElem;
    bf16* Vt = Kp + NElem;
    float2* tab = (float2*)(Vt + NElem);

    dim3 g(64, 8);
    rope_tab_k<<<256, blk, 0, stream>>>(tab);
    cvt_pair<<<4608, blk, 0, stream>>>(q, buf0, w_q, wbuf);
    mha_gemm<0><<<g, blk, 0, stream>>>(buf0, wbuf, (void*)Qp, tab);
    cvt_pair<<<4608, blk, 0, stream>>>(k, buf0, w_k, wbuf);
    mha_gemm<0><<<g, blk, 0, stream>>>(buf0, wbuf, (void*)Kp, tab);
    cvt_pair<<<4608, blk, 0, stream>>>(v, buf0, w_v, wbuf);
    mha_gemm<1><<<g, blk, 0, stream>>>(buf0, wbuf, (void*)Vt, tab);
    mha_attn<<<dim3(16, 64), blk, 0, stream>>>(Qp, Kp, Vt, mask, buf0);
    cvt_w<<<512, blk, 0, stream>>>(w_o, wbuf);
    mha_gemm<2><<<g, blk, 0, stream>>>(buf0, wbuf, (void*)out, tab);
  }
}

// Round 9
// 363.964 us; speedup vs baseline: 1.0338x; 1.0338x over previous
//
#include <hip/hip_runtime.h>
#include <hip/hip_bf16.h>
#include <math.h>

// MHA block: B=4, S=2048, D=1024, H=16, DK=64.
// R12 (resubmit after 2nd infra failure; pipeline logic re-audited: vmcnt
// accounting, WAR ordering, barrier uniformity all sound; m139 ran this
// pattern on HW): GEMM K-loop re-pipelined — 3-stage LDS rotation with
// COUNTED vmcnt. Theory: per-iteration pipe-busy is ~500 cyc but measured
// ~1800 => ~70% exposed stall; co-resident blocks stall in lockstep so
// cross-block overlap never materializes (why R7/R8 were null). Fix: issue
// tile kt+2 at iteration kt; barrier waits vmcnt(4) so tile kt+1 is done but
// kt+2 stays in flight (T4). LDS 48KB -> 3 blocks/CU. R11 regressions
// reverted (attn setprio removed, rope table removed).

namespace {

constexpr int Bb = 4, Ss = 2048, Dd = 1024, Hh = 16, DKk = 64;
constexpr size_t NElem = (size_t)Bb * Hh * Ss * DKk;  // 8388608
constexpr size_t WElem = (size_t)Dd * Dd;             // 1048576

typedef __bf16 bf16;
typedef __attribute__((ext_vector_type(8))) __bf16 bf16x8;
typedef __attribute__((ext_vector_type(4))) float f32x4;

__device__ __forceinline__ bf16x8 pack8(float4 a, float4 b) {
  bf16x8 r;
  r[0] = (__bf16)a.x; r[1] = (__bf16)a.y; r[2] = (__bf16)a.z; r[3] = (__bf16)a.w;
  r[4] = (__bf16)b.x; r[5] = (__bf16)b.y; r[6] = (__bf16)b.z; r[7] = (__bf16)b.w;
  return r;
}

__device__ __forceinline__ void gl_lds16(const bf16* g, bf16* l) {
  __builtin_amdgcn_global_load_lds((const __attribute__((address_space(1))) void*)g,
                                   (__attribute__((address_space(3))) void*)l, 16, 0, 0);
}

// fused fp32->bf16: blocks [0,12288) convert q,k,v (4096 each);
// [12288,14336) convert wq,wk,wv,wo (512 each).
__global__ __launch_bounds__(256) void cvt6(const float* __restrict__ q,
                                            const float* __restrict__ k,
                                            const float* __restrict__ v,
                                            const float* __restrict__ wq,
                                            const float* __restrict__ wk,
                                            const float* __restrict__ wv,
                                            const float* __restrict__ wo,
                                            bf16* __restrict__ xd, bf16* __restrict__ wd) {
  const int bid = blockIdx.x;
  const float* s; bf16* d; size_t idx;
  if (bid < 12288) {
    const int t = bid >> 12;
    s = (t == 0) ? q : (t == 1) ? k : v;
    d = xd + (size_t)t * NElem;
    idx = ((size_t)(bid & 4095) * 256 + threadIdx.x) * 8;
  } else {
    const int t = (bid - 12288) >> 9;
    s = (t == 0) ? wq : (t == 1) ? wk : (t == 2) ? wv : wo;
    d = wd + (size_t)t * WElem;
    idx = ((size_t)((bid - 12288) & 511) * 256 + threadIdx.x) * 8;
  }
  float4 f0 = *(const float4*)(s + idx), f1 = *(const float4*)(s + idx + 4);
  *(bf16x8*)(d + idx) = pack8(f0, f1);
}

// legacy pair-convert for the fallback path
__global__ __launch_bounds__(256) void cvt_pair(const float* __restrict__ x, bf16* __restrict__ xd,
                                                const float* __restrict__ ws, bf16* __restrict__ wd) {
  const int bid = blockIdx.x;
  const float* s; bf16* d; size_t idx;
  if (bid < 4096) { s = x; d = xd; idx = (size_t)bid * 256 + threadIdx.x; }
  else { s = ws; d = wd; idx = (size_t)(bid - 4096) * 256 + threadIdx.x; }
  idx *= 8;
  float4 f0 = *(const float4*)(s + idx), f1 = *(const float4*)(s + idx + 4);
  *(bf16x8*)(d + idx) = pack8(f0, f1);
}

__global__ __launch_bounds__(256) void cvt_w(const float* __restrict__ ws, bf16* __restrict__ wd) {
  size_t idx = ((size_t)blockIdx.x * 256 + threadIdx.x) * 8;
  float4 f0 = *(const float4*)(ws + idx), f1 = *(const float4*)(ws + idx + 4);
  *(bf16x8*)(wd + idx) = pack8(f0, f1);
}

// C = A(8192x1024) * W(1024x1024)^T, bf16 in, 128x128 tile, BK=32, 4 waves (2x2 of 64x64).
// 3-stage gl_lds pipeline, counted vmcnt(4) at the barrier (tile kt+1 done,
// kt+2 in flight). MODE 0: rope-store; 1: V-transpose-store; 2: fp32 plain
// store; 3: fused QKV (blockIdx.z selects tensor; z<2 rope, z==2 transpose).
template <int MODE>
__global__ __launch_bounds__(256, 3) void mha_gemm(const bf16* __restrict__ A,
                                                   const bf16* __restrict__ W,
                                                   void* __restrict__ dstv) {
  __shared__ __align__(16) bf16 As[3][128][32];
  __shared__ __align__(16) bf16 Bs[3][128][32];
  const int tid = threadIdx.x;
  const int z = (MODE == 3) ? blockIdx.z : 0;
  const int bm0 = blockIdx.x * 128, bn0 = blockIdx.y * 128;
  const int w = tid >> 6, lane = tid & 63, l16 = lane & 15, quad = lane >> 4;
  const int wm = (w >> 1) * 64, wn = (w & 1) * 64;
  const int lr = lane >> 2, lc = (lane & 3) * 8;

  const bf16* Ag = A + (size_t)z * NElem + (size_t)(bm0 + w * 32 + lr) * Dd + lc;
  const bf16* Wg = W + (size_t)z * WElem + (size_t)(bn0 + w * 32 + lr) * Dd + lc;

  f32x4 acc[4][4] = {};

#define STAGE(buf, kt)                                      \
  do {                                                      \
    const int ko_ = (kt) * 32;                              \
    gl_lds16(Ag + ko_, &As[(buf)][w * 32][0]);              \
    gl_lds16(Ag + ko_ + 16 * Dd, &As[(buf)][w * 32 + 16][0]); \
    gl_lds16(Wg + ko_, &Bs[(buf)][w * 32][0]);              \
    gl_lds16(Wg + ko_ + 16 * Dd, &Bs[(buf)][w * 32 + 16][0]); \
  } while (0)

  // prologue: tiles 0,1 in flight; wait only tile 0 (oldest 4 of 8)
  STAGE(0, 0);
  STAGE(1, 1);
  asm volatile("s_waitcnt vmcnt(4)" ::: "memory");
  __builtin_amdgcn_s_barrier();
  __builtin_amdgcn_sched_barrier(0);

  int cur = 0, stb = 2;  // buffer holding tile kt; stage target = (kt+2)%3
  for (int kt = 0; kt < 32; ++kt) {
    if (kt < 30) STAGE(stb, kt + 2);

    bf16x8 af[4], bw[4];
#pragma unroll
    for (int i = 0; i < 4; ++i) af[i] = *(bf16x8*)&As[cur][wm + i * 16 + l16][quad * 8];
#pragma unroll
    for (int i = 0; i < 4; ++i) bw[i] = *(bf16x8*)&Bs[cur][wn + i * 16 + l16][quad * 8];
#pragma unroll
    for (int mt = 0; mt < 4; ++mt)
#pragma unroll
      for (int nt = 0; nt < 4; ++nt)
        acc[mt][nt] =
            __builtin_amdgcn_mfma_f32_16x16x32_bf16(af[mt], bw[nt], acc[mt][nt], 0, 0, 0);

    // counted wait: tile kt+1's loads (oldest 4) complete; kt+2's stay in flight
    __builtin_amdgcn_sched_barrier(0);
    if (kt < 30) {
      asm volatile("s_waitcnt vmcnt(4)" ::: "memory");
    } else {
      asm volatile("s_waitcnt vmcnt(0)" ::: "memory");
    }
    __builtin_amdgcn_s_barrier();
    __builtin_amdgcn_sched_barrier(0);

    cur = (cur == 2) ? 0 : cur + 1;
    stb = (stb == 2) ? 0 : stb + 1;
  }
#undef STAGE

  // C/D layout: col = lane&15, row = quad*4 + r
  const bool do_rope = (MODE == 0) || (MODE == 3 && z < 2);
  const bool do_vt = (MODE == 1) || (MODE == 3 && z == 2);

  if constexpr (MODE == 2) {
    float* out = (float*)dstv;
#pragma unroll
    for (int mt = 0; mt < 4; ++mt)
#pragma unroll
      for (int nt = 0; nt < 4; ++nt) {
        const int gcol = bn0 + wn + nt * 16 + l16;
        const int grow0 = bm0 + wm + mt * 16 + quad * 4;
#pragma unroll
        for (int r = 0; r < 4; ++r) out[(size_t)(grow0 + r) * Dd + gcol] = acc[mt][nt][r];
      }
  } else {
    if (do_vt) {
      bf16* vt = (bf16*)dstv + (MODE == 3 ? 2 * NElem : 0);
#pragma unroll
      for (int mt = 0; mt < 4; ++mt)
#pragma unroll
        for (int nt = 0; nt < 4; ++nt) {
          const int gcol = bn0 + wn + nt * 16 + l16;
          const int h = gcol >> 6, dk = gcol & 63;
#pragma unroll
          for (int r = 0; r < 4; ++r) {
            const int grow = bm0 + wm + mt * 16 + quad * 4 + r;
            const int b = grow >> 11, s = grow & (Ss - 1);
            vt[((size_t)(b * Hh + h) * DKk + dk) * Ss + s] = (bf16)acc[mt][nt][r];
          }
        }
    } else if (do_rope) {
      bf16* qp = (bf16*)dstv + (MODE == 3 ? (size_t)z * NElem : 0);
#pragma unroll
      for (int mt = 0; mt < 4; ++mt)
#pragma unroll
        for (int nt = 0; nt < 4; ++nt) {
          const int gcol = bn0 + wn + nt * 16 + l16;
          const int h = gcol >> 6, dk = gcol & 63;
          const float invf = exp2f((float)(dk >> 1) * -0.4152410118609203f);
          const float sgn = (dk & 1) ? 1.0f : -1.0f;
#pragma unroll
          for (int r = 0; r < 4; ++r) {
            const int grow = bm0 + wm + mt * 16 + quad * 4 + r;
            const int b = grow >> 11, s = grow & (Ss - 1);
            const float v = acc[mt][nt][r];
            const float ov = __shfl_xor(v, 1);
            float sn, cs;
            __sincosf((float)s * invf, &sn, &cs);
            const float rot = v * cs + sgn * ov * sn;
            qp[((size_t)(b * Hh + h) * Ss + s) * DKk + dk] = (bf16)rot;
          }
        }
    }
  }
}

// Flash attention (R10 structure, setprio removed): 128 q-rows x one (b,h) per
// block; 4 waves x 32 rows; 64-key tiles, double-buffered gl_lds; mask folded
// into MFMA acc init (bias -96 = -c2/c1, p = exp2(s*c1)); l via ones-MFMA;
// per-kt phase split with single-pass kf/vf reads.
// LDS: Ks 16K dbuf + Vs 16K dbuf + P 8K = 40960 B -> 4 blocks/CU.
__global__ __launch_bounds__(256, 4) void mha_attn(const bf16* __restrict__ Qp,
                                                   const bf16* __restrict__ Kp,
                                                   const bf16* __restrict__ Vt,
                                                   const int* __restrict__ maskG,
                                                   bf16* __restrict__ Xo) {
  __shared__ __align__(16) bf16 Ks[2][64][64];  // [buf][key][dk], XOR-swizzled 16B chunks
  __shared__ __align__(16) bf16 Vs[2][64][64];  // [buf][dk][key], XOR-swizzled 16B chunks
  __shared__ __align__(16) bf16 Pbuf[4][1024];  // per-wave P slice (16 rows x 64 keys)

  constexpr float c1 = 0.18033688011112042f;   // 0.125 * log2(e)
  // c2 = -12*log2(e) folded into acc-init bias: -c2/c1 = -96 exactly.

  const int tid = threadIdx.x;
  const int bh = blockIdx.y, b = bh >> 4, h = bh & 15;
  const int q0 = blockIdx.x * 128;
  const int w = tid >> 6, lane = tid & 63, l16 = lane & 15, quad = lane >> 4;
  const int swz = l16 & 7;
  const size_t hbase = (size_t)bh * Ss * DKk;

  {  // stage Q tile [128 x 64] through the Ks dbuf area (8192 elts, exactly fits)
    bf16* Qst = &Ks[0][0][0];
    const int row = tid >> 1, hf = tid & 1;
    const bf16* src = Qp + hbase + (size_t)(q0 + row) * DKk + hf * 32;
#pragma unroll
    for (int cc = 0; cc < 4; ++cc)
      *(int4*)&Qst[(((hf * 4 + cc) * 128) + row) * 8] = *(const int4*)(src + cc * 8);
  }
  __syncthreads();
  // hoist Q fragments (A-layout: m -> q-row w*32+mt*16+l16, k=kk*32+quad*8+j)
  bf16x8 qf[2][2];
  {
    const bf16* Qst = &Ks[0][0][0];
#pragma unroll
    for (int mt = 0; mt < 2; ++mt)
#pragma unroll
      for (int kk = 0; kk < 2; ++kk)
        qf[mt][kk] = *(bf16x8*)&Qst[(((kk * 4 + quad) * 128) + w * 32 + mt * 16 + l16) * 8];
  }
  __syncthreads();  // all hoists done before K DMA overwrites Ks

  // staging lane geometry: 8 rows x 8 chunks per issue; swizzle chunk ^= row&7
  const int srow = lane >> 3, schunk = (lane & 7) ^ (srow & 7);
  const bf16* Kg = Kp + hbase + (size_t)(w * 16 + srow) * DKk + schunk * 8;
  const bf16* Vg = Vt + ((size_t)bh * DKk + w * 16 + srow) * Ss + schunk * 8;
  const int* Mg = maskG + b * Ss + l16;

  int mcur[4], mnext[4];
  // prologue: stage tile 0
#pragma unroll
  for (int i = 0; i < 2; ++i) {
    gl_lds16(Kg + (size_t)i * 8 * DKk, &Ks[0][w * 16 + i * 8][0]);
    gl_lds16(Vg + i * 8 * Ss, &Vs[0][w * 16 + i * 8][0]);
  }
#pragma unroll
  for (int nt = 0; nt < 4; ++nt) mcur[nt] = Mg[nt * 16];
  __syncthreads();  // drains tile-0 DMA

  f32x4 o[2][4] = {};
  f32x4 lo[2] = {};
  bf16* Pb = &Pbuf[w][0];

  // ones B-operand for the l-accumulating MFMA (registers only, no LDS)
  bf16x8 vones;
#pragma unroll
  for (int i = 0; i < 8; ++i) vones[i] = (__bf16)1.0f;

  for (int kt = 0; kt < 32; ++kt) {
    const int cur = kt & 1, nxt = cur ^ 1;
    if (kt < 31) {  // prefetch tile kt+1 (drained at this iteration's end barrier)
      const size_t k0n = (size_t)(kt + 1) * 64;
#pragma unroll
      for (int i = 0; i < 2; ++i) {
        gl_lds16(Kg + k0n * DKk + (size_t)i * 8 * DKk, &Ks[nxt][w * 16 + i * 8][0]);
        gl_lds16(Vg + k0n + i * 8 * Ss, &Vs[nxt][w * 16 + i * 8][0]);
      }
#pragma unroll
      for (int nt = 0; nt < 4; ++nt) mnext[nt] = Mg[k0n + nt * 16];
    }

    // ---- QK phase: S = Q K^T for BOTH mt, each kf read ONCE ----
    // bias init: unmasked -96 (= -c2/c1), masked -1e9 -> exp2 underflows to 0
    f32x4 sc[2][4];
#pragma unroll
    for (int nt = 0; nt < 4; ++nt) {
      const float bv = (mcur[nt] != 0) ? -96.0f : -1e9f;
#pragma unroll
      for (int r = 0; r < 4; ++r) { sc[0][nt][r] = bv; sc[1][nt][r] = bv; }
    }
#pragma unroll
    for (int kk = 0; kk < 2; ++kk)
#pragma unroll
      for (int nt = 0; nt < 4; ++nt) {
        bf16x8 kf = *(bf16x8*)&Ks[cur][nt * 16 + l16][((kk * 4 + quad) ^ swz) * 8];
        sc[0][nt] = __builtin_amdgcn_mfma_f32_16x16x32_bf16(qf[0][kk], kf, sc[0][nt], 0, 0, 0);
        sc[1][nt] = __builtin_amdgcn_mfma_f32_16x16x32_bf16(qf[1][kk], kf, sc[1][nt], 0, 0, 0);
      }

    // ---- softmax + P staging, mt0 then mt1 through the SAME Pb slice ----
    // (same-wave DS ops execute in order: write mt0 -> read pf0 -> write mt1
    //  -> read pf1 is safe)
    bf16x8 pf0[2], pf1[2];
#pragma unroll
    for (int nt = 0; nt < 4; ++nt) {
      const int c = nt * 2 + (l16 >> 3);
      const int jj = l16 & 7;
#pragma unroll
      for (int r = 0; r < 4; ++r)
        Pb[(c * 16 + quad * 4 + r) * 8 + jj] = (bf16)exp2f(sc[0][nt][r] * c1);
    }
#pragma unroll
    for (int kk = 0; kk < 2; ++kk)
      pf0[kk] = *(bf16x8*)(Pb + ((kk * 4 + quad) * 16 + l16) * 8);
#pragma unroll
    for (int nt = 0; nt < 4; ++nt) {
      const int c = nt * 2 + (l16 >> 3);
      const int jj = l16 & 7;
#pragma unroll
      for (int r = 0; r < 4; ++r)
        Pb[(c * 16 + quad * 4 + r) * 8 + jj] = (bf16)exp2f(sc[1][nt][r] * c1);
    }
#pragma unroll
    for (int kk = 0; kk < 2; ++kk)
      pf1[kk] = *(bf16x8*)(Pb + ((kk * 4 + quad) * 16 + l16) * 8);

    // ---- PV phase: each vf read ONCE, feeds both mt; l via ones-MFMA ----
#pragma unroll
    for (int kk = 0; kk < 2; ++kk) {
      lo[0] = __builtin_amdgcn_mfma_f32_16x16x32_bf16(pf0[kk], vones, lo[0], 0, 0, 0);
      lo[1] = __builtin_amdgcn_mfma_f32_16x16x32_bf16(pf1[kk], vones, lo[1], 0, 0, 0);
#pragma unroll
      for (int nt = 0; nt < 4; ++nt) {
        bf16x8 vf = *(bf16x8*)&Vs[cur][nt * 16 + l16][((kk * 4 + quad) ^ swz) * 8];
        o[0][nt] = __builtin_amdgcn_mfma_f32_16x16x32_bf16(pf0[kk], vf, o[0][nt], 0, 0, 0);
        o[1][nt] = __builtin_amdgcn_mfma_f32_16x16x32_bf16(pf1[kk], vf, o[1][nt], 0, 0, 0);
      }
    }
    __syncthreads();  // all waves done with buf cur; prefetch of nxt drained here
#pragma unroll
    for (int nt = 0; nt < 4; ++nt) mcur[nt] = mnext[nt];
  }

  // epilogue: O / l -> Xo [B*S, H*DK] bf16  (lo identical across the 16 cols of a row)
#pragma unroll
  for (int mt = 0; mt < 2; ++mt)
#pragma unroll
    for (int nt = 0; nt < 4; ++nt)
#pragma unroll
      for (int r = 0; r < 4; ++r) {
        const int srw = q0 + w * 32 + mt * 16 + quad * 4 + r;
        const int dk = nt * 16 + l16;
        Xo[(size_t)(b * Ss + srw) * Dd + h * DKk + dk] = (bf16)(o[mt][nt][r] / lo[mt][r]);
      }
}

}  // namespace

extern "C" void kernel_launch(void* const* d_in, const int* in_sizes, int n_in,
                              void* d_out, int out_size, void* d_ws, size_t ws_size,
                              hipStream_t stream) {
  (void)in_sizes; (void)n_in; (void)out_size;
  const float* q = (const float*)d_in[0];
  const float* k = (const float*)d_in[1];
  const float* v = (const float*)d_in[2];
  const int* mask = (const int*)d_in[3];
  const float* w_q = (const float*)d_in[4];
  const float* w_k = (const float*)d_in[5];
  const float* w_v = (const float*)d_in[6];
  const float* w_o = (const float*)d_in[7];
  float* out = (float*)d_out;

  dim3 blk(256);
  const size_t fused_bytes = (6 * NElem + 4 * WElem) * sizeof(bf16);  // ~109 MB

  if (ws_size >= fused_bytes) {
    // fused path: Ab = xq,xk,xv bf16 | Wb = wq,wk,wv,wo bf16 | Db = Qp,Kp,Vt
    bf16* Ab = (bf16*)d_ws;
    bf16* Wb = Ab + 3 * NElem;
    bf16* Db = Wb + 4 * WElem;
    bf16* Qp = Db;
    bf16* Kp = Db + NElem;
    bf16* Vt = Db + 2 * NElem;
    bf16* Xo = Ab;  // xq dead after QKV GEMMs

    cvt6<<<14336, blk, 0, stream>>>(q, k, v, w_q, w_k, w_v, w_o, Ab, Wb);
    mha_gemm<3><<<dim3(64, 8, 3), blk, 0, stream>>>(Ab, Wb, (void*)Db);
    mha_attn<<<dim3(16, 64), blk, 0, stream>>>(Qp, Kp, Vt, mask, Xo);
    mha_gemm<2><<<dim3(64, 8), blk, 0, stream>>>(Xo, Wb + 3 * WElem, (void*)out);
  } else {
    // fallback: sequential (R7 layout, 69.2 MB)
    bf16* buf0 = (bf16*)d_ws;
    bf16* wbuf = buf0 + NElem;
    bf16* Qp = wbuf + WElem;
    bf16* Kp = Qp + NElem;
    bf16* Vt = Kp + NElem;

    dim3 g(64, 8);
    cvt_pair<<<4608, blk, 0, stream>>>(q, buf0, w_q, wbuf);
    mha_gemm<0><<<g, blk, 0, stream>>>(buf0, wbuf, (void*)Qp);
    cvt_pair<<<4608, blk, 0, stream>>>(k, buf0, w_k, wbuf);
    mha_gemm<0><<<g, blk, 0, stream>>>(buf0, wbuf, (void*)Kp);
    cvt_pair<<<4608, blk, 0, stream>>>(v, buf0, w_v, wbuf);
    mha_gemm<1><<<g, blk, 0, stream>>>(buf0, wbuf, (void*)Vt);
    mha_attn<<<dim3(16, 64), blk, 0, stream>>>(Qp, Kp, Vt, mask, buf0);
    cvt_w<<<512, blk, 0, stream>>>(w_o, wbuf);
    mha_gemm<2><<<g, blk, 0, stream>>>(buf0, wbuf, (void*)out);
  }
}